// Round 17
// baseline (223.349 us; speedup 1.0000x reference)
//
#include <hip/hip_runtime.h>
#include <hip/hip_bf16.h>
#include <math.h>

// Shapes (fixed by the reference)
#define B_   128
#define W_   512
#define D_   2048
#define H_   16
#define DH_  128

typedef __attribute__((ext_vector_type(4))) float f32x4;
typedef __attribute__((ext_vector_type(8))) short bf16x8;

typedef const __attribute__((address_space(1))) void* gvp;
typedef __attribute__((address_space(3))) void* lvp;

__device__ inline short f2bf(float f) {
  union { __hip_bfloat16 h; short s; } u;
  u.h = __float2bfloat16(f);
  return u.s;
}
__device__ inline float bf2f(unsigned short u) {
  return __uint_as_float(((unsigned)u) << 16);
}

// truncation-pack 8 fp32 -> 8 bf16 (4 v_perm), 16B result
__device__ inline void pack8_trunc(const float* f, void* dst) {
  unsigned u[4];
#pragma unroll
  for (int j = 0; j < 4; ++j)
    u[j] = __builtin_amdgcn_perm(__float_as_uint(f[2 * j + 1]),
                                 __float_as_uint(f[2 * j]), 0x07060302u);
  *(uint4*)dst = *(const uint4*)u;
}

// raw barrier: drain LDS ops but NOT in-flight global_load_lds (vmcnt).
#define LGKM_BARRIER() do {                                   \
    asm volatile("s_waitcnt lgkmcnt(0)" ::: "memory");        \
    __builtin_amdgcn_sched_barrier(0);                        \
    __builtin_amdgcn_s_barrier();                             \
    __builtin_amdgcn_sched_barrier(0);                        \
  } while (0)

// full drain barrier: vmcnt(0) + lgkmcnt(0) + s_barrier
#define VM_LGKM_BARRIER() do {                                \
    asm volatile("s_waitcnt vmcnt(0) lgkmcnt(0)" ::: "memory"); \
    __builtin_amdgcn_sched_barrier(0);                        \
    __builtin_amdgcn_s_barrier();                             \
    __builtin_amdgcn_sched_barrier(0);                        \
  } while (0)

// ---------------------------------------------------------------------------
// bf16 MFMA GEMM, M = 128 always.  C[m,n] = sum_k A[m,k] * B[n,k].
// AMODE 0: A fp32 (+ optional A2 concat switch at a2_k).
// AMODE 1: A = part_a (bf16 two-half flash partials) combined with ml.
// TWK flat-grid merged dispatch:
//   [0,256)     g1 gemm (n0=(bid&31)*64, ks=bid>>5, params as passed)
//   [256,1280)  Wk transpose into twk_dst
//   [1280,1408) g6a gemm: same A (=x), B=g6B (row stride 2*D_), C=g6C,
//               Kblk=512, ks=(bid-1280)>>5 in [0,4)
// ---------------------------------------------------------------------------
template<bool BBF16, int AMODE, bool TWK>
__global__ __launch_bounds__(256) void gemm_mfma(
    const float* __restrict__ A, int a_rs, long a_hs,
    const float* __restrict__ A2, int a2_k,
    const void* __restrict__ Bv, int b_rs, long b_hs,
    float* __restrict__ C, int c_rs, long c_hs, long c_ks,
    int Kblk,
    const float* __restrict__ twk_src, unsigned short* __restrict__ twk_dst,
    const float* __restrict__ g6B, float* __restrict__ g6C)
{
  __shared__ char sm[2][24576];

  const int t  = threadIdx.x;

  if (TWK) {
    if (blockIdx.x >= 256 && blockIdx.x < 1280) {
      // ---- transpose body: WkT[h][e][d] (bf16) = Wk[h*128+d][e]
      float (*tile)[68] = (float(*)[68])sm;
      const int tb  = blockIdx.x - 256;
      const int e0t = (tb & 31) * 64;
      const int d0  = ((tb >> 5) & 1) * 64;
      const int hh  = tb >> 6;
      {
        int d = t >> 2, eq = (t & 3) * 16;
        const float* src = twk_src + (long)(hh * DH_ + d0 + d) * D_ + e0t + eq;
#pragma unroll
        for (int qq = 0; qq < 4; ++qq)
          *(float4*)&tile[d][eq + qq * 4] = *(const float4*)(src + qq * 4);
      }
      __syncthreads();
      {
        int e = t >> 2, dq = (t & 3) * 16;
        unsigned short* dst = twk_dst + ((long)hh * D_ + e0t + e) * DH_ + d0 + dq;
        float f0[8], f1[8];
#pragma unroll
        for (int j = 0; j < 8; ++j) f0[j] = tile[dq + j][e];
#pragma unroll
        for (int j = 0; j < 8; ++j) f1[j] = tile[dq + 8 + j][e];
        pack8_trunc(f0, dst);
        pack8_trunc(f1, dst + 8);
      }
      return;
    }
  }

  // effective (block-uniform) params — g6a blocks override
  const void* Bv_eff = Bv;
  float* C_eff = C;
  int Kblk_eff = Kblk;
  int brs_eff = b_rs;
  int bid = blockIdx.x;
  if (TWK && bid >= 1280) {
    bid -= 1280;
    Bv_eff = g6B; C_eff = g6C; Kblk_eff = 512; brs_eff = 2 * D_;
  }

  const int w  = t >> 6, l = t & 63, lo = l & 15, hi = l >> 4;
  const int wm = w >> 1, wn = w & 1;
  const int n0   = TWK ? ((bid & 31) * 64) : (blockIdx.x * 64);
  const int head = TWK ? 0 : blockIdx.y;
  const int ks   = TWK ? (bid >> 5) : blockIdx.z;
  const int kbeg = ks * Kblk_eff;
  const int nit  = Kblk_eff >> 6;

  const float* Ab = nullptr;
  if (AMODE == 0) {
    const float* base = A;
    int koff = kbeg;
    if (A2 && kbeg >= a2_k) { base = A2; koff = kbeg - a2_k; }
    Ab = base + head * a_hs + koff;
  }
  const float*          Bf = (const float*)Bv_eff      + (BBF16 ? 0 : head * b_hs + (long)n0 * brs_eff + kbeg);
  const unsigned short* Bh = (const unsigned short*)Bv_eff + (BBF16 ? head * b_hs + (long)n0 * brs_eff + kbeg : 0);

  const int ar = t >> 2;
  const int ak = (t & 3) * 16;

  f32x4 acc[4][2] = {};

  auto load_tiles = [&](int it, float4* ar4, float4* br4) {
    if (AMODE == 0) {
      const float* Ait = Ab + it * 64;
#pragma unroll
      for (int p = 0; p < 2; ++p) {
        const float* src = Ait + (long)(p * 64 + ar) * a_rs + ak;
#pragma unroll
        for (int qq = 0; qq < 4; ++qq) ar4[p * 4 + qq] = *(const float4*)(src + qq * 4);
      }
    } else {
      const unsigned short* pa = (const unsigned short*)A;
      const float* mlp = A2;
      const int col = kbeg + it * 64 + ak;
#pragma unroll
      for (int p = 0; p < 2; ++p) {
        int m  = p * 64 + ar;
        int bh = m * 16 + head;
        float m0 = mlp[bh * 2],              l0 = mlp[bh * 2 + 1];
        float m1 = mlp[(2048 + bh) * 2],     l1 = mlp[(2048 + bh) * 2 + 1];
        float M  = fmaxf(m0, m1);
        float w0 = __expf(m0 - M), w1 = __expf(m1 - M);
        float inv = 1.0f / (w0 * l0 + w1 * l1);
        w0 *= inv; w1 *= inv;
        const unsigned short* r0 = pa + (long)bh * D_ + col;
        const unsigned short* r1 = r0 + (long)B_ * H_ * D_;
#pragma unroll
        for (int q2 = 0; q2 < 2; ++q2) {
          bf16x8 a0 = *(const bf16x8*)(r0 + q2 * 8);
          bf16x8 a1 = *(const bf16x8*)(r1 + q2 * 8);
          float out[8];
#pragma unroll
          for (int j = 0; j < 8; ++j)
            out[j] = w0 * bf2f((unsigned short)a0[j]) + w1 * bf2f((unsigned short)a1[j]);
          ar4[p * 4 + q2 * 2]     = make_float4(out[0], out[1], out[2], out[3]);
          ar4[p * 4 + q2 * 2 + 1] = make_float4(out[4], out[5], out[6], out[7]);
        }
      }
    }
    if (BBF16) {
      const char* src = (const char*)(Bh + (long)ar * brs_eff + it * 64 + ak);
      br4[0] = *(const float4*)(src);
      br4[1] = *(const float4*)(src + 16);
    } else {
      const float* src = Bf + (long)ar * brs_eff + it * 64 + ak;
#pragma unroll
      for (int qq = 0; qq < 4; ++qq) br4[qq] = *(const float4*)(src + qq * 4);
    }
  };

  auto write_tiles = [&](int buf, const float4* ar4, const float4* br4) {
    char* As = sm[buf];
    char* Bs = sm[buf] + 16384;
#pragma unroll
    for (int p = 0; p < 2; ++p) {
      int m = p * 64 + ar;
      int base = m * 128 + ak * 2;
      int swz = (m & 7) << 4;
      const float* f = (const float*)(ar4 + p * 4);
#pragma unroll
      for (int h2 = 0; h2 < 2; ++h2)
        pack8_trunc(f + h2 * 8, As + ((base + h2 * 16) ^ swz));
    }
    {
      int n = ar;
      int base = n * 128 + ak * 2;
      int swz = (n & 7) << 4;
      if (BBF16) {
#pragma unroll
        for (int h2 = 0; h2 < 2; ++h2)
          *(bf16x8*)(Bs + ((base + h2 * 16) ^ swz)) = ((const bf16x8*)br4)[h2];
      } else {
        const float* f = (const float*)br4;
#pragma unroll
        for (int h2 = 0; h2 < 2; ++h2)
          pack8_trunc(f + h2 * 8, Bs + ((base + h2 * 16) ^ swz));
      }
    }
  };

  auto compute = [&](int buf) {
    const char* As = sm[buf];
    const char* Bs = sm[buf] + 16384;
#pragma unroll
    for (int kk = 0; kk < 2; ++kk) {
      bf16x8 af[4], bfr[2];
#pragma unroll
      for (int mi = 0; mi < 4; ++mi) {
        int m = wm * 64 + mi * 16 + lo;
        af[mi] = *(const bf16x8*)(As + ((m * 128 + (kk * 32 + hi * 8) * 2) ^ ((m & 7) << 4)));
      }
#pragma unroll
      for (int ni = 0; ni < 2; ++ni) {
        int n = wn * 32 + ni * 16 + lo;
        bfr[ni] = *(const bf16x8*)(Bs + ((n * 128 + (kk * 32 + hi * 8) * 2) ^ ((n & 7) << 4)));
      }
#pragma unroll
      for (int mi = 0; mi < 4; ++mi)
#pragma unroll
        for (int ni = 0; ni < 2; ++ni)
          acc[mi][ni] = __builtin_amdgcn_mfma_f32_16x16x32_bf16(af[mi], bfr[ni], acc[mi][ni], 0, 0, 0);
    }
  };

  float4 ar4[8], br4[4];
  load_tiles(0, ar4, br4);
  write_tiles(0, ar4, br4);
  __syncthreads();
  for (int it = 0; it < nit; ++it) {
    float4 na[8], nb[4];
    if (it + 1 < nit) load_tiles(it + 1, na, nb);
    compute(it & 1);
    if (it + 1 < nit) write_tiles((it + 1) & 1, na, nb);
    __syncthreads();
  }

  float* Cb = C_eff + c_ks * ks + c_hs * head + n0;
#pragma unroll
  for (int mi = 0; mi < 4; ++mi)
#pragma unroll
    for (int ni = 0; ni < 2; ++ni)
#pragma unroll
      for (int r = 0; r < 4; ++r)
        Cb[(long)(wm * 64 + mi * 16 + hi * 4 + r) * c_rs + (wn * 32 + ni * 16 + lo)] = acc[mi][ni][r];
}

// ---------------------------------------------------------------------------
// vectorized K-split reduce: out4[i] = sum_{k<8} part4[k*stride4 + i]
// grid 256 x 256: exactly 65536 float4 elements.
// ---------------------------------------------------------------------------
__global__ __launch_bounds__(256) void reduce_add_k(
    const float* __restrict__ part, long stride4, float* __restrict__ out)
{
  const long i = (long)blockIdx.x * 256 + threadIdx.x;   // float4 index
  const f32x4* p4 = (const f32x4*)part;
  f32x4 s = p4[i];
#pragma unroll
  for (int k = 1; k < 8; ++k) s += p4[k * stride4 + i];
  ((f32x4*)out)[i] = s;
}

// ---------------------------------------------------------------------------
// Fused flash attention v8 (R13/R14/R16, frozen): counted-vmcnt pipeline.
// ---------------------------------------------------------------------------
__global__ __launch_bounds__(1024, 4) void fused_attn(
    const float* __restrict__ x, const float* __restrict__ buffer,
    const float* __restrict__ qt, unsigned short* __restrict__ part,
    float* __restrict__ ml)
{
  __shared__ float kv[2 * 8 * 2048];   // 128 KiB, two 8-row fp32 tiles
  __shared__ float lacc[16][9][20];    // partials [wave][s][h], padded
  __shared__ float pbuf[16][8];        // P fp32 [h][s]
  __shared__ float sbuf[16];           // per-h rescale factor

  const int b    = blockIdx.x;
  const int half = blockIdx.y;
  const int t    = threadIdx.x;
  const int w    = t >> 6;
  const int lane = t & 63;
  const int lo   = lane & 15;
  const int hi   = lane >> 4;
  const char* kvb = (const char*)kv;

  bf16x8 afrag[4];
  {
    const float* qrow = qt + ((long)b * H_ + lo) * D_;
    const float sc = 0.088388347648318447f;  // 1/sqrt(128)
#pragma unroll
    for (int kk = 0; kk < 4; ++kk) {
      int e0 = w * 128 + kk * 32 + hi * 8;
      float4 qa = *(const float4*)(qrow + e0);
      float4 qb = *(const float4*)(qrow + e0 + 4);
      afrag[kk][0] = f2bf(qa.x * sc); afrag[kk][1] = f2bf(qa.y * sc);
      afrag[kk][2] = f2bf(qa.z * sc); afrag[kk][3] = f2bf(qa.w * sc);
      afrag[kk][4] = f2bf(qb.x * sc); afrag[kk][5] = f2bf(qb.y * sc);
      afrag[kk][6] = f2bf(qb.z * sc); afrag[kk][7] = f2bf(qb.w * sc);
    }
  }

  float accE[16][2];
#pragma unroll
  for (int h = 0; h < 16; ++h) { accE[h][0] = 0.f; accE[h][1] = 0.f; }
  float m_run = -1e30f, l_run = 0.f;   // per wave: head w's online state

  auto stage = [&](int sb, int tl) {
#pragma unroll
    for (int r = 0; r < 4; ++r) {
      int s = r * 2 + (w >> 3);
      int inrow = (w & 7) * 1024 + lane * 16;
      int srco = inrow ^ (s << 4);
      int s_glob = half * 256 + tl * 8 + s;
      const float* row = (s_glob < W_ - 1)
          ? buffer + (((long)(b * W_ + s_glob + 1)) << 11)
          : x + ((long)b << 11);
      __builtin_amdgcn_global_load_lds(
          (gvp)(row + (srco >> 2)),
          (lvp)(kv + sb * 16384 + r * 4096 + w * 256), 16, 0, 0);
    }
  };

  // prologue: kv0 resident, stage(1) in flight
  stage(0, 0);
  VM_LGKM_BARRIER();
  stage(1, 1);

  for (int tile = 0; tile < 32; ++tile) {
    const int buf  = tile & 1;
    const int bufo = buf * 65536;

    // ---- partial logits over this wave's e-band (MFMA, v_perm pack)
    {
      f32x4 c4 = {0.f, 0.f, 0.f, 0.f};
      const int srow = lo & 7;
#pragma unroll
      for (int kk = 0; kk < 4; ++kk) {
        unsigned B0 = (unsigned)(srow * 8192 + (w * 128 + kk * 32 + hi * 8) * 4);
        unsigned o1 = B0 ^ (unsigned)(srow << 4);
        float4 f1 = *(const float4*)(kvb + bufo + o1);
        float4 f2 = *(const float4*)(kvb + bufo + (o1 ^ 16u));
        unsigned u[4];
        u[0] = __builtin_amdgcn_perm(__float_as_uint(f1.y), __float_as_uint(f1.x), 0x07060302u);
        u[1] = __builtin_amdgcn_perm(__float_as_uint(f1.w), __float_as_uint(f1.z), 0x07060302u);
        u[2] = __builtin_amdgcn_perm(__float_as_uint(f2.y), __float_as_uint(f2.x), 0x07060302u);
        u[3] = __builtin_amdgcn_perm(__float_as_uint(f2.w), __float_as_uint(f2.z), 0x07060302u);
        bf16x8 bf;
        __builtin_memcpy(&bf, u, 16);
        c4 = __builtin_amdgcn_mfma_f32_16x16x32_bf16(afrag[kk], bf, c4, 0, 0, 0);
      }
      if (lo < 8) *(f32x4*)&lacc[w][lo][hi * 4] = c4;
    }

    // ---- hoisted PV kv reads (all kv[buf] reads end here, pre-B1)
    float2 kvp[8];
    {
      const unsigned ebyte = (unsigned)((w * 128 + lane * 2) * 4);
#pragma unroll
      for (int s = 0; s < 8; ++s) {
        unsigned Bx = (unsigned)(s * 8192) + ebyte;
        kvp[s] = *(const float2*)(kvb + bufo + (Bx ^ (unsigned)(s << 4)));
      }
    }
    LGKM_BARRIER();                    // B1: lacc visible; kv[buf] reads done

    // issue stage(t+2) into kv[buf] NOW (freed: all reads were pre-B1)
    if (tile + 2 < 32) stage(buf, tile + 2);

    // ---- 16-wave online softmax: wave w owns head w
    {
      const int s   = lane & 7;
      const int wwg = lane >> 3;
      float v = lacc[wwg][s][w] + lacc[wwg + 8][s][w];
      v += __shfl_xor(v, 8);
      v += __shfl_xor(v, 16);
      v += __shfl_xor(v, 32);
      float mt = v;
      mt = fmaxf(mt, __shfl_xor(mt, 1));
      mt = fmaxf(mt, __shfl_xor(mt, 2));
      mt = fmaxf(mt, __shfl_xor(mt, 4));
      float m_new = fmaxf(m_run, mt);
      float scl = __expf(m_run - m_new);
      float p = __expf(v - m_new);
      float ps = p;
      ps += __shfl_xor(ps, 1);
      ps += __shfl_xor(ps, 2);
      ps += __shfl_xor(ps, 4);
      l_run = l_run * scl + ps;
      m_run = m_new;
      if (lane < 8) pbuf[w][lane] = p;
      if (lane == 0) sbuf[w] = scl;
    }
    // B2: publish pbuf/sbuf AND drain stage(t+1) while keeping stage(t+2)
    // in flight.  Tail: vmcnt(0).
    if (tile < 30) {
      asm volatile("s_waitcnt vmcnt(4) lgkmcnt(0)" ::: "memory");
    } else {
      asm volatile("s_waitcnt vmcnt(0) lgkmcnt(0)" ::: "memory");
    }
    __builtin_amdgcn_sched_barrier(0);
    __builtin_amdgcn_s_barrier();
    __builtin_amdgcn_sched_barrier(0);

    // ---- rescale + PV (fp32 VALU, regs + pbuf/sbuf only)
#pragma unroll
    for (int h = 0; h < 16; ++h) {
      float scl = sbuf[h];
      float a0 = accE[h][0] * scl, a1 = accE[h][1] * scl;
      float4 pA = *(const float4*)&pbuf[h][0];
      float4 pB = *(const float4*)&pbuf[h][4];
      a0 += pA.x * kvp[0].x + pA.y * kvp[1].x + pA.z * kvp[2].x + pA.w * kvp[3].x
          + pB.x * kvp[4].x + pB.y * kvp[5].x + pB.z * kvp[6].x + pB.w * kvp[7].x;
      a1 += pA.x * kvp[0].y + pA.y * kvp[1].y + pA.z * kvp[2].y + pA.w * kvp[3].y
          + pB.x * kvp[4].y + pB.y * kvp[5].y + pB.z * kvp[6].y + pB.w * kvp[7].y;
      accE[h][0] = a0; accE[h][1] = a1;
    }
    // no trailing barrier: next-iteration B1 orders pbuf reuse
  }

  // ---- epilogue: unnormalized acc (bf16) + (m,l)
  {
    long base = ((long)half * B_ + b) * H_;
#pragma unroll
    for (int h = 0; h < 16; ++h) {
      long idx = (base + h) * D_ + w * 128 + lane * 2;
      unsigned u0 = (unsigned short)f2bf(accE[h][0]);
      unsigned u1 = (unsigned short)f2bf(accE[h][1]);
      *(unsigned*)(part + idx) = u0 | (u1 << 16);
    }
    if (lane == 0) {
      ml[(base + w) * 2 + 0] = m_run;
      ml[(base + w) * 2 + 1] = l_run;
    }
  }
}

// ---------------------------------------------------------------------------
// gate epilogue (float4): z = sum8 g6b + sum4 g6a + bg;
// y = x + sigmoid(z)*out1.  grid 256 x 256 over 65536 float4 elements.
// ---------------------------------------------------------------------------
__global__ __launch_bounds__(256) void gate_final_k(
    const float* __restrict__ p6b, const float* __restrict__ p6a,
    const float* __restrict__ bg, const float* __restrict__ x,
    const float* __restrict__ out1, float* __restrict__ y)
{
  const long i = (long)blockIdx.x * 256 + threadIdx.x;   // float4 index
  const f32x4* pb = (const f32x4*)p6b;
  const f32x4* pa = (const f32x4*)p6a;
  f32x4 z = ((const f32x4*)bg)[i & (D_ / 4 - 1)];
#pragma unroll
  for (int k = 0; k < 8; ++k) z += pb[(long)k * (B_ * D_ / 4) + i];
#pragma unroll
  for (int k = 0; k < 4; ++k) z += pa[(long)k * (B_ * D_ / 4) + i];
  f32x4 xv = ((const f32x4*)x)[i];
  f32x4 ov = ((const f32x4*)out1)[i];
  f32x4 r;
#pragma unroll
  for (int j = 0; j < 4; ++j) {
    float g = 1.0f / (1.0f + __expf(-z[j]));
    r[j] = xv[j] + g * ov[j];
  }
  ((f32x4*)y)[i] = r;
}

// ---------------------------------------------------------------------------
extern "C" void kernel_launch(void* const* d_in, const int* in_sizes, int n_in,
                              void* d_out, int out_size, void* d_ws, size_t ws_size,
                              hipStream_t stream)
{
  const float* x      = (const float*)d_in[0];
  const float* buffer = (const float*)d_in[1];
  const float* Wq     = (const float*)d_in[2];
  const float* Wk     = (const float*)d_in[3];
  const float* Wv     = (const float*)d_in[4];
  const float* Wo     = (const float*)d_in[5];
  const float* Wg     = (const float*)d_in[6];
  const float* bg     = (const float*)d_in[7];
  float* y = (float*)d_out;

  // workspace layout (float units) — R14 layout + g6a region appended
  float* ws    = (float*)d_ws;
  float* q     = ws;                        // 262144
  float* qt    = ws + 262144;               // 4194304
  unsigned short* part_a = (unsigned short*)(ws + 4456448); // 8388608 bf16
  float* ml    = ws + 8650752;              // 8192
  float* o0    = ws + 8658944;              // 262144
  float* o1    = ws + 8921088;              // 262144
  float* partg = ws + 9183232;              // 8 * 262144 = 2097152
  unsigned short* wkT = (unsigned short*)(ws + 11280384);   // 4194304 bf16
  float* p6a   = ws + 13377536;             // 4 * 262144 = 1048576 (g6a)

  const long S = (long)B_ * D_;

  // 1) merged dispatch: g1 (q-partials, blocks 0-255) + Wk transpose
  //    (256-1279) + g6a = x @ Wg[:, :2048].T (1280-1407, ksplit 4)
  gemm_mfma<false, 0, true><<<dim3(1408), 256, 0, stream>>>(
      x, D_, 0, nullptr, 1 << 30, Wq, D_, 0, partg, D_, 0, S, 256,
      Wk, wkT, Wg, p6a);
  reduce_add_k<<<256, 256, 0, stream>>>(partg, S / 4, q);

  // 2) qt[b,h,e] = sum_d q[b,h*128+d] * WkT[h][e][d]   (K=128, per-head)
  gemm_mfma<true, 0, false><<<dim3(32, 16, 1), 256, 0, stream>>>(
      q, D_, DH_, nullptr, 1 << 30, wkT, DH_, (long)D_ * DH_,
      qt, H_ * D_, D_, 0, DH_, nullptr, nullptr, nullptr, nullptr);

  // 3) fused flash attention (combine folded into step 4's A-staging)
  fused_attn<<<dim3(B_, 2), 1024, 0, stream>>>(x, buffer, qt, part_a, ml);

  // 4) o0[b,h*128+d] = sum_e combine(part_a,ml)[b,h,e] * Wv[h*128+d,e]
  gemm_mfma<false, 1, false><<<dim3(2, 16, 8), 256, 0, stream>>>(
      (const float*)part_a, 0, 0, ml, 0, Wv, D_, (long)DH_ * D_,
      partg, D_, DH_, S, 256, nullptr, nullptr, nullptr, nullptr);
  reduce_add_k<<<256, 256, 0, stream>>>(partg, S / 4, o0);

  // 5) o1 = o0 @ Wo.T
  gemm_mfma<false, 0, false><<<dim3(32, 1, 8), 256, 0, stream>>>(
      o0, D_, 0, nullptr, 1 << 30, Wo, D_, 0, partg, D_, 0, S, 256,
      nullptr, nullptr, nullptr, nullptr);
  reduce_add_k<<<256, 256, 0, stream>>>(partg, S / 4, o1);

  // 6) g6b: z2-partials = o1 @ Wg[:, 2048:].T  (K=2048, ksplit 8)
  gemm_mfma<false, 0, false><<<dim3(32, 1, 8), 256, 0, stream>>>(
      o1, D_, 0, nullptr, 1 << 30, Wg + D_, 2 * D_, 0, partg, D_, 0, S, 256,
      nullptr, nullptr, nullptr, nullptr);
  gate_final_k<<<256, 256, 0, stream>>>(partg, p6a, bg, x, o1, y);

  (void)in_sizes; (void)n_in; (void)out_size; (void)ws_size;
}

// Round 18
// 212.575 us; speedup vs baseline: 1.0507x; 1.0507x over previous
//
#include <hip/hip_runtime.h>
#include <hip/hip_bf16.h>
#include <math.h>

// Shapes (fixed by the reference)
#define B_   128
#define W_   512
#define D_   2048
#define H_   16
#define DH_  128

typedef __attribute__((ext_vector_type(4))) float f32x4;
typedef __attribute__((ext_vector_type(8))) short bf16x8;

typedef const __attribute__((address_space(1))) void* gvp;
typedef __attribute__((address_space(3))) void* lvp;

__device__ inline short f2bf(float f) {
  union { __hip_bfloat16 h; short s; } u;
  u.h = __float2bfloat16(f);
  return u.s;
}
__device__ inline float bf2f(unsigned short u) {
  return __uint_as_float(((unsigned)u) << 16);
}

// truncation-pack 8 fp32 -> 8 bf16 (4 v_perm), 16B result
__device__ inline void pack8_trunc(const float* f, void* dst) {
  unsigned u[4];
#pragma unroll
  for (int j = 0; j < 4; ++j)
    u[j] = __builtin_amdgcn_perm(__float_as_uint(f[2 * j + 1]),
                                 __float_as_uint(f[2 * j]), 0x07060302u);
  *(uint4*)dst = *(const uint4*)u;
}

// raw barrier: drain LDS ops but NOT in-flight global_load_lds (vmcnt).
#define LGKM_BARRIER() do {                                   \
    asm volatile("s_waitcnt lgkmcnt(0)" ::: "memory");        \
    __builtin_amdgcn_sched_barrier(0);                        \
    __builtin_amdgcn_s_barrier();                             \
    __builtin_amdgcn_sched_barrier(0);                        \
  } while (0)

// full drain barrier: vmcnt(0) + lgkmcnt(0) + s_barrier
#define VM_LGKM_BARRIER() do {                                \
    asm volatile("s_waitcnt vmcnt(0) lgkmcnt(0)" ::: "memory"); \
    __builtin_amdgcn_sched_barrier(0);                        \
    __builtin_amdgcn_s_barrier();                             \
    __builtin_amdgcn_sched_barrier(0);                        \
  } while (0)

// ---------------------------------------------------------------------------
// bf16 MFMA GEMM, M = 128 always.  C[m,n] = sum_k A[m,k] * B[n,k].
// AMODE 0: A fp32 (+ optional A2 concat switch at a2_k).
// AMODE 1: A = part_a (bf16 two-half flash partials) combined with ml.
// TWK: launched with a flat 1D grid; blocks [0,256) do the gemm
//   (n0=(bid&31)*64, head=0, ks=bid>>5), blocks [256,1280) transpose Wk
//   into WkT (independent work overlapped with the gemm).
// ---------------------------------------------------------------------------
template<bool BBF16, int AMODE, bool TWK>
__global__ __launch_bounds__(256) void gemm_mfma(
    const float* __restrict__ A, int a_rs, long a_hs,
    const float* __restrict__ A2, int a2_k,
    const void* __restrict__ Bv, int b_rs, long b_hs,
    float* __restrict__ C, int c_rs, long c_hs, long c_ks,
    int Kblk,
    const float* __restrict__ twk_src, unsigned short* __restrict__ twk_dst)
{
  __shared__ char sm[2][24576];

  const int t  = threadIdx.x;

  if (TWK) {
    if (blockIdx.x >= 256) {
      // ---- transpose body: WkT[h][e][d] (bf16) = Wk[h*128+d][e]
      float (*tile)[68] = (float(*)[68])sm;
      const int tb  = blockIdx.x - 256;
      const int e0t = (tb & 31) * 64;
      const int d0  = ((tb >> 5) & 1) * 64;
      const int hh  = tb >> 6;
      {
        int d = t >> 2, eq = (t & 3) * 16;
        const float* src = twk_src + (long)(hh * DH_ + d0 + d) * D_ + e0t + eq;
#pragma unroll
        for (int qq = 0; qq < 4; ++qq)
          *(float4*)&tile[d][eq + qq * 4] = *(const float4*)(src + qq * 4);
      }
      __syncthreads();
      {
        int e = t >> 2, dq = (t & 3) * 16;
        unsigned short* dst = twk_dst + ((long)hh * D_ + e0t + e) * DH_ + d0 + dq;
        float f0[8], f1[8];
#pragma unroll
        for (int j = 0; j < 8; ++j) f0[j] = tile[dq + j][e];
#pragma unroll
        for (int j = 0; j < 8; ++j) f1[j] = tile[dq + 8 + j][e];
        pack8_trunc(f0, dst);
        pack8_trunc(f1, dst + 8);
      }
      return;
    }
  }

  const int w  = t >> 6, l = t & 63, lo = l & 15, hi = l >> 4;
  const int wm = w >> 1, wn = w & 1;
  const int n0   = TWK ? ((blockIdx.x & 31) * 64) : (blockIdx.x * 64);
  const int head = TWK ? 0 : blockIdx.y;
  const int ks   = TWK ? ((int)blockIdx.x >> 5) : blockIdx.z;
  const int kbeg = ks * Kblk;
  const int nit  = Kblk >> 6;

  const float* Ab = nullptr;
  if (AMODE == 0) {
    const float* base = A;
    int koff = kbeg;
    if (A2 && kbeg >= a2_k) { base = A2; koff = kbeg - a2_k; }
    Ab = base + head * a_hs + koff;
  }
  const float*          Bf = (const float*)Bv          + (BBF16 ? 0 : head * b_hs + (long)n0 * b_rs + kbeg);
  const unsigned short* Bh = (const unsigned short*)Bv + (BBF16 ? head * b_hs + (long)n0 * b_rs + kbeg : 0);

  const int ar = t >> 2;
  const int ak = (t & 3) * 16;

  f32x4 acc[4][2] = {};

  auto load_tiles = [&](int it, float4* ar4, float4* br4) {
    if (AMODE == 0) {
      const float* Ait = Ab + it * 64;
#pragma unroll
      for (int p = 0; p < 2; ++p) {
        const float* src = Ait + (long)(p * 64 + ar) * a_rs + ak;
#pragma unroll
        for (int qq = 0; qq < 4; ++qq) ar4[p * 4 + qq] = *(const float4*)(src + qq * 4);
      }
    } else {
      const unsigned short* pa = (const unsigned short*)A;
      const float* mlp = A2;
      const int col = kbeg + it * 64 + ak;
#pragma unroll
      for (int p = 0; p < 2; ++p) {
        int m  = p * 64 + ar;
        int bh = m * 16 + head;
        float m0 = mlp[bh * 2],              l0 = mlp[bh * 2 + 1];
        float m1 = mlp[(2048 + bh) * 2],     l1 = mlp[(2048 + bh) * 2 + 1];
        float M  = fmaxf(m0, m1);
        float w0 = __expf(m0 - M), w1 = __expf(m1 - M);
        float inv = 1.0f / (w0 * l0 + w1 * l1);
        w0 *= inv; w1 *= inv;
        const unsigned short* r0 = pa + (long)bh * D_ + col;
        const unsigned short* r1 = r0 + (long)B_ * H_ * D_;
#pragma unroll
        for (int q2 = 0; q2 < 2; ++q2) {
          bf16x8 a0 = *(const bf16x8*)(r0 + q2 * 8);
          bf16x8 a1 = *(const bf16x8*)(r1 + q2 * 8);
          float out[8];
#pragma unroll
          for (int j = 0; j < 8; ++j)
            out[j] = w0 * bf2f((unsigned short)a0[j]) + w1 * bf2f((unsigned short)a1[j]);
          ar4[p * 4 + q2 * 2]     = make_float4(out[0], out[1], out[2], out[3]);
          ar4[p * 4 + q2 * 2 + 1] = make_float4(out[4], out[5], out[6], out[7]);
        }
      }
    }
    if (BBF16) {
      const char* src = (const char*)(Bh + (long)ar * b_rs + it * 64 + ak);
      br4[0] = *(const float4*)(src);
      br4[1] = *(const float4*)(src + 16);
    } else {
      const float* src = Bf + (long)ar * b_rs + it * 64 + ak;
#pragma unroll
      for (int qq = 0; qq < 4; ++qq) br4[qq] = *(const float4*)(src + qq * 4);
    }
  };

  auto write_tiles = [&](int buf, const float4* ar4, const float4* br4) {
    char* As = sm[buf];
    char* Bs = sm[buf] + 16384;
#pragma unroll
    for (int p = 0; p < 2; ++p) {
      int m = p * 64 + ar;
      int base = m * 128 + ak * 2;
      int swz = (m & 7) << 4;
      const float* f = (const float*)(ar4 + p * 4);
#pragma unroll
      for (int h2 = 0; h2 < 2; ++h2)
        pack8_trunc(f + h2 * 8, As + ((base + h2 * 16) ^ swz));
    }
    {
      int n = ar;
      int base = n * 128 + ak * 2;
      int swz = (n & 7) << 4;
      if (BBF16) {
#pragma unroll
        for (int h2 = 0; h2 < 2; ++h2)
          *(bf16x8*)(Bs + ((base + h2 * 16) ^ swz)) = ((const bf16x8*)br4)[h2];
      } else {
        const float* f = (const float*)br4;
#pragma unroll
        for (int h2 = 0; h2 < 2; ++h2)
          pack8_trunc(f + h2 * 8, Bs + ((base + h2 * 16) ^ swz));
      }
    }
  };

  auto compute = [&](int buf) {
    const char* As = sm[buf];
    const char* Bs = sm[buf] + 16384;
#pragma unroll
    for (int kk = 0; kk < 2; ++kk) {
      bf16x8 af[4], bfr[2];
#pragma unroll
      for (int mi = 0; mi < 4; ++mi) {
        int m = wm * 64 + mi * 16 + lo;
        af[mi] = *(const bf16x8*)(As + ((m * 128 + (kk * 32 + hi * 8) * 2) ^ ((m & 7) << 4)));
      }
#pragma unroll
      for (int ni = 0; ni < 2; ++ni) {
        int n = wn * 32 + ni * 16 + lo;
        bfr[ni] = *(const bf16x8*)(Bs + ((n * 128 + (kk * 32 + hi * 8) * 2) ^ ((n & 7) << 4)));
      }
#pragma unroll
      for (int mi = 0; mi < 4; ++mi)
#pragma unroll
        for (int ni = 0; ni < 2; ++ni)
          acc[mi][ni] = __builtin_amdgcn_mfma_f32_16x16x32_bf16(af[mi], bfr[ni], acc[mi][ni], 0, 0, 0);
    }
  };

  float4 ar4[8], br4[4];
  load_tiles(0, ar4, br4);
  write_tiles(0, ar4, br4);
  __syncthreads();
  for (int it = 0; it < nit; ++it) {
    float4 na[8], nb[4];
    if (it + 1 < nit) load_tiles(it + 1, na, nb);
    compute(it & 1);
    if (it + 1 < nit) write_tiles((it + 1) & 1, na, nb);
    __syncthreads();
  }

  float* Cb = C + c_ks * ks + c_hs * head + n0;
#pragma unroll
  for (int mi = 0; mi < 4; ++mi)
#pragma unroll
    for (int ni = 0; ni < 2; ++ni)
#pragma unroll
      for (int r = 0; r < 4; ++r)
        Cb[(long)(wm * 64 + mi * 16 + hi * 4 + r) * c_rs + (wn * 32 + ni * 16 + lo)] = acc[mi][ni][r];
}

// ---------------------------------------------------------------------------
// vectorized K-split reduce: out4[i] = sum_{k<8} part4[k*stride4 + i]
// grid 256 x 256: exactly 65536 float4 elements.
// ---------------------------------------------------------------------------
__global__ __launch_bounds__(256) void reduce_add_k(
    const float* __restrict__ part, long stride4, float* __restrict__ out)
{
  const long i = (long)blockIdx.x * 256 + threadIdx.x;   // float4 index
  const f32x4* p4 = (const f32x4*)part;
  f32x4 s = p4[i];
#pragma unroll
  for (int k = 1; k < 8; ++k) s += p4[k * stride4 + i];
  ((f32x4*)out)[i] = s;
}

// ---------------------------------------------------------------------------
// Fused flash attention v8 (R13/R14, frozen): counted-vmcnt pipeline, 2
// barriers/tile, stage(t+2) post-B1, vmcnt(4) at B2 (vmcnt(0) tail).
// R16: afrag prologue loads vectorized (float4).
// ---------------------------------------------------------------------------
__global__ __launch_bounds__(1024, 4) void fused_attn(
    const float* __restrict__ x, const float* __restrict__ buffer,
    const float* __restrict__ qt, unsigned short* __restrict__ part,
    float* __restrict__ ml)
{
  __shared__ float kv[2 * 8 * 2048];   // 128 KiB, two 8-row fp32 tiles
  __shared__ float lacc[16][9][20];    // partials [wave][s][h], padded
  __shared__ float pbuf[16][8];        // P fp32 [h][s]
  __shared__ float sbuf[16];           // per-h rescale factor

  const int b    = blockIdx.x;
  const int half = blockIdx.y;
  const int t    = threadIdx.x;
  const int w    = t >> 6;
  const int lane = t & 63;
  const int lo   = lane & 15;
  const int hi   = lane >> 4;
  const char* kvb = (const char*)kv;

  bf16x8 afrag[4];
  {
    const float* qrow = qt + ((long)b * H_ + lo) * D_;
    const float sc = 0.088388347648318447f;  // 1/sqrt(128)
#pragma unroll
    for (int kk = 0; kk < 4; ++kk) {
      int e0 = w * 128 + kk * 32 + hi * 8;
      float4 qa = *(const float4*)(qrow + e0);
      float4 qb = *(const float4*)(qrow + e0 + 4);
      afrag[kk][0] = f2bf(qa.x * sc); afrag[kk][1] = f2bf(qa.y * sc);
      afrag[kk][2] = f2bf(qa.z * sc); afrag[kk][3] = f2bf(qa.w * sc);
      afrag[kk][4] = f2bf(qb.x * sc); afrag[kk][5] = f2bf(qb.y * sc);
      afrag[kk][6] = f2bf(qb.z * sc); afrag[kk][7] = f2bf(qb.w * sc);
    }
  }

  float accE[16][2];
#pragma unroll
  for (int h = 0; h < 16; ++h) { accE[h][0] = 0.f; accE[h][1] = 0.f; }
  float m_run = -1e30f, l_run = 0.f;   // per wave: head w's online state

  auto stage = [&](int sb, int tl) {
#pragma unroll
    for (int r = 0; r < 4; ++r) {
      int s = r * 2 + (w >> 3);
      int inrow = (w & 7) * 1024 + lane * 16;
      int srco = inrow ^ (s << 4);
      int s_glob = half * 256 + tl * 8 + s;
      const float* row = (s_glob < W_ - 1)
          ? buffer + (((long)(b * W_ + s_glob + 1)) << 11)
          : x + ((long)b << 11);
      __builtin_amdgcn_global_load_lds(
          (gvp)(row + (srco >> 2)),
          (lvp)(kv + sb * 16384 + r * 4096 + w * 256), 16, 0, 0);
    }
  };

  // prologue: kv0 resident, stage(1) in flight
  stage(0, 0);
  VM_LGKM_BARRIER();
  stage(1, 1);

  for (int tile = 0; tile < 32; ++tile) {
    const int buf  = tile & 1;
    const int bufo = buf * 65536;

    // ---- partial logits over this wave's e-band (MFMA, v_perm pack)
    {
      f32x4 c4 = {0.f, 0.f, 0.f, 0.f};
      const int srow = lo & 7;
#pragma unroll
      for (int kk = 0; kk < 4; ++kk) {
        unsigned B0 = (unsigned)(srow * 8192 + (w * 128 + kk * 32 + hi * 8) * 4);
        unsigned o1 = B0 ^ (unsigned)(srow << 4);
        float4 f1 = *(const float4*)(kvb + bufo + o1);
        float4 f2 = *(const float4*)(kvb + bufo + (o1 ^ 16u));
        unsigned u[4];
        u[0] = __builtin_amdgcn_perm(__float_as_uint(f1.y), __float_as_uint(f1.x), 0x07060302u);
        u[1] = __builtin_amdgcn_perm(__float_as_uint(f1.w), __float_as_uint(f1.z), 0x07060302u);
        u[2] = __builtin_amdgcn_perm(__float_as_uint(f2.y), __float_as_uint(f2.x), 0x07060302u);
        u[3] = __builtin_amdgcn_perm(__float_as_uint(f2.w), __float_as_uint(f2.z), 0x07060302u);
        bf16x8 bf;
        __builtin_memcpy(&bf, u, 16);
        c4 = __builtin_amdgcn_mfma_f32_16x16x32_bf16(afrag[kk], bf, c4, 0, 0, 0);
      }
      if (lo < 8) *(f32x4*)&lacc[w][lo][hi * 4] = c4;
    }

    // ---- hoisted PV kv reads (all kv[buf] reads end here, pre-B1)
    float2 kvp[8];
    {
      const unsigned ebyte = (unsigned)((w * 128 + lane * 2) * 4);
#pragma unroll
      for (int s = 0; s < 8; ++s) {
        unsigned Bx = (unsigned)(s * 8192) + ebyte;
        kvp[s] = *(const float2*)(kvb + bufo + (Bx ^ (unsigned)(s << 4)));
      }
    }
    LGKM_BARRIER();                    // B1: lacc visible; kv[buf] reads done

    // issue stage(t+2) into kv[buf] NOW (freed: all reads were pre-B1);
    // its loads ride across B2 via the counted vmcnt below.
    if (tile + 2 < 32) stage(buf, tile + 2);

    // ---- 16-wave online softmax: wave w owns head w
    {
      const int s   = lane & 7;
      const int wwg = lane >> 3;
      float v = lacc[wwg][s][w] + lacc[wwg + 8][s][w];
      v += __shfl_xor(v, 8);
      v += __shfl_xor(v, 16);
      v += __shfl_xor(v, 32);
      float mt = v;
      mt = fmaxf(mt, __shfl_xor(mt, 1));
      mt = fmaxf(mt, __shfl_xor(mt, 2));
      mt = fmaxf(mt, __shfl_xor(mt, 4));
      float m_new = fmaxf(m_run, mt);
      float scl = __expf(m_run - m_new);
      float p = __expf(v - m_new);
      float ps = p;
      ps += __shfl_xor(ps, 1);
      ps += __shfl_xor(ps, 2);
      ps += __shfl_xor(ps, 4);
      l_run = l_run * scl + ps;
      m_run = m_new;
      if (lane < 8) pbuf[w][lane] = p;
      if (lane == 0) sbuf[w] = scl;
    }
    // B2: publish pbuf/sbuf AND drain stage(t+1) (oldest 4 loads) while
    // keeping stage(t+2) (newest 4) in flight.  Tail: vmcnt(0).
    if (tile < 30) {
      asm volatile("s_waitcnt vmcnt(4) lgkmcnt(0)" ::: "memory");
    } else {
      asm volatile("s_waitcnt vmcnt(0) lgkmcnt(0)" ::: "memory");
    }
    __builtin_amdgcn_sched_barrier(0);
    __builtin_amdgcn_s_barrier();
    __builtin_amdgcn_sched_barrier(0);

    // ---- rescale + PV (fp32 VALU, regs + pbuf/sbuf only)
#pragma unroll
    for (int h = 0; h < 16; ++h) {
      float scl = sbuf[h];
      float a0 = accE[h][0] * scl, a1 = accE[h][1] * scl;
      float4 pA = *(const float4*)&pbuf[h][0];
      float4 pB = *(const float4*)&pbuf[h][4];
      a0 += pA.x * kvp[0].x + pA.y * kvp[1].x + pA.z * kvp[2].x + pA.w * kvp[3].x
          + pB.x * kvp[4].x + pB.y * kvp[5].x + pB.z * kvp[6].x + pB.w * kvp[7].x;
      a1 += pA.x * kvp[0].y + pA.y * kvp[1].y + pA.z * kvp[2].y + pA.w * kvp[3].y
          + pB.x * kvp[4].y + pB.y * kvp[5].y + pB.z * kvp[6].y + pB.w * kvp[7].y;
      accE[h][0] = a0; accE[h][1] = a1;
    }
    // no trailing barrier: next-iteration B1 orders pbuf reuse
  }

  // ---- epilogue: unnormalized acc (bf16) + (m,l)
  {
    long base = ((long)half * B_ + b) * H_;
#pragma unroll
    for (int h = 0; h < 16; ++h) {
      long idx = (base + h) * D_ + w * 128 + lane * 2;
      unsigned u0 = (unsigned short)f2bf(accE[h][0]);
      unsigned u1 = (unsigned short)f2bf(accE[h][1]);
      *(unsigned*)(part + idx) = u0 | (u1 << 16);
    }
    if (lane == 0) {
      ml[(base + w) * 2 + 0] = m_run;
      ml[(base + w) * 2 + 1] = l_run;
    }
  }
}

// ---------------------------------------------------------------------------
// gate epilogue (float4): z = sum8 part + bg; y = x + sigmoid(z)*out1
// grid 256 x 256 over 65536 float4 elements.
// ---------------------------------------------------------------------------
__global__ __launch_bounds__(256) void gate_final_k(
    const float* __restrict__ part, const float* __restrict__ bg,
    const float* __restrict__ x, const float* __restrict__ out1,
    float* __restrict__ y)
{
  const long i = (long)blockIdx.x * 256 + threadIdx.x;   // float4 index
  const f32x4* p4 = (const f32x4*)part;
  f32x4 z = ((const f32x4*)bg)[i & (D_ / 4 - 1)];
#pragma unroll
  for (int k = 0; k < 8; ++k) z += p4[(long)k * (B_ * D_ / 4) + i];
  f32x4 xv = ((const f32x4*)x)[i];
  f32x4 ov = ((const f32x4*)out1)[i];
  f32x4 r;
#pragma unroll
  for (int j = 0; j < 4; ++j) {
    float g = 1.0f / (1.0f + __expf(-z[j]));
    r[j] = xv[j] + g * ov[j];
  }
  ((f32x4*)y)[i] = r;
}

// ---------------------------------------------------------------------------
extern "C" void kernel_launch(void* const* d_in, const int* in_sizes, int n_in,
                              void* d_out, int out_size, void* d_ws, size_t ws_size,
                              hipStream_t stream)
{
  const float* x      = (const float*)d_in[0];
  const float* buffer = (const float*)d_in[1];
  const float* Wq     = (const float*)d_in[2];
  const float* Wk     = (const float*)d_in[3];
  const float* Wv     = (const float*)d_in[4];
  const float* Wo     = (const float*)d_in[5];
  const float* Wg     = (const float*)d_in[6];
  const float* bg     = (const float*)d_in[7];
  float* y = (float*)d_out;

  // workspace layout (float units) — R14's proven layout
  float* ws    = (float*)d_ws;
  float* q     = ws;                        // 262144
  float* qt    = ws + 262144;               // 4194304
  unsigned short* part_a = (unsigned short*)(ws + 4456448); // 8388608 bf16
  float* ml    = ws + 8650752;              // 8192
  float* o0    = ws + 8658944;              // 262144
  float* o1    = ws + 8921088;              // 262144
  float* partg = ws + 9183232;              // 8 * 262144 = 2097152
  unsigned short* wkT = (unsigned short*)(ws + 11280384);   // 16*2048*128 bf16

  const long S = (long)B_ * D_;

  // 1) q-partials = x @ Wq.T  (K=2048, ksplit 8)  +  Wk transpose merged
  //    (blocks 0..255 gemm, 256..1279 transpose — independent, overlapped)
  gemm_mfma<false, 0, true><<<dim3(1280), 256, 0, stream>>>(
      x, D_, 0, nullptr, 1 << 30, Wq, D_, 0, partg, D_, 0, S, 256, Wk, wkT);
  reduce_add_k<<<256, 256, 0, stream>>>(partg, S / 4, q);

  // 2) qt[b,h,e] = sum_d q[b,h*128+d] * WkT[h][e][d]   (K=128, per-head)
  gemm_mfma<true, 0, false><<<dim3(32, 16, 1), 256, 0, stream>>>(
      q, D_, DH_, nullptr, 1 << 30, wkT, DH_, (long)D_ * DH_,
      qt, H_ * D_, D_, 0, DH_, nullptr, nullptr);

  // 3) fused flash attention (combine folded into step 4's A-staging)
  fused_attn<<<dim3(B_, 2), 1024, 0, stream>>>(x, buffer, qt, part_a, ml);

  // 4) o0[b,h*128+d] = sum_e combine(part_a,ml)[b,h,e] * Wv[h*128+d,e]
  gemm_mfma<false, 1, false><<<dim3(2, 16, 8), 256, 0, stream>>>(
      (const float*)part_a, 0, 0, ml, 0, Wv, D_, (long)DH_ * D_,
      partg, D_, DH_, S, 256, nullptr, nullptr);
  reduce_add_k<<<256, 256, 0, stream>>>(partg, S / 4, o0);

  // 5) o1 = o0 @ Wo.T
  gemm_mfma<false, 0, false><<<dim3(32, 1, 8), 256, 0, stream>>>(
      o0, D_, 0, nullptr, 1 << 30, Wo, D_, 0, partg, D_, 0, S, 256,
      nullptr, nullptr);
  reduce_add_k<<<256, 256, 0, stream>>>(partg, S / 4, o1);

  // 6) gate: z = concat(x,o1) @ Wg.T + bg   (K=4096, A-switch at 2048)
  gemm_mfma<false, 0, false><<<dim3(32, 1, 8), 256, 0, stream>>>(
      x, D_, 0, o1, D_, Wg, 2 * D_, 0, partg, D_, 0, S, 512,
      nullptr, nullptr);
  gate_final_k<<<256, 256, 0, stream>>>(partg, bg, x, o1, y);

  (void)in_sizes; (void)n_in; (void)out_size; (void)ws_size;
}